// Round 1
// baseline (229.039 us; speedup 1.0000x reference)
//
#include <hip/hip_runtime.h>

// Haar DWT along axis 1 of (8, 4096, 1024) fp32.
// cA[b,j,c] = (x[b,2j,c] + x[b,2j+1,c]) * 1/sqrt(2)
// cD[b,j,c] = (x[b,2j,c] - x[b,2j+1,c]) * 1/sqrt(2)
// d_out = [cA flat | cD flat].
//
// Memory-bound streamer: float4 per thread, exact grid, fully coalesced.

#define NPAIR_VEC (8 * 2048 * 256)   // float4 elements per output half

__global__ __launch_bounds__(256) void dwt_haar_kernel(
    const float4* __restrict__ x,
    float4* __restrict__ cA,
    float4* __restrict__ cD)
{
    const float k = 0.7071067811865476f;
    const int i = blockIdx.x * 256 + threadIdx.x;   // [0, NPAIR_VEC)
    const int r = i >> 8;        // global pair-row index (b*2048 + j)
    const int c = i & 255;       // float4 column within row
    const int e = r * 512 + c;   // even input row (2r) in float4 units

    const float4 a = x[e];        // x[b, 2j, c..c+3]
    const float4 b = x[e + 256];  // x[b, 2j+1, c..c+3]

    float4 s, d;
    s.x = (a.x + b.x) * k;  d.x = (a.x - b.x) * k;
    s.y = (a.y + b.y) * k;  d.y = (a.y - b.y) * k;
    s.z = (a.z + b.z) * k;  d.z = (a.z - b.z) * k;
    s.w = (a.w + b.w) * k;  d.w = (a.w - b.w) * k;

    cA[i] = s;
    cD[i] = d;
}

extern "C" void kernel_launch(void* const* d_in, const int* in_sizes, int n_in,
                              void* d_out, int out_size, void* d_ws, size_t ws_size,
                              hipStream_t stream)
{
    const float4* x = (const float4*)d_in[0];
    float4* cA = (float4*)d_out;
    float4* cD = cA + NPAIR_VEC;

    const int nblocks = NPAIR_VEC / 256;  // 16384
    dwt_haar_kernel<<<nblocks, 256, 0, stream>>>(x, cA, cD);
}

// Round 3
// 220.031 us; speedup vs baseline: 1.0409x; 1.0409x over previous
//
#include <hip/hip_runtime.h>

// Haar DWT along axis 1 of (8, 4096, 1024) fp32.
// cA[b,j,c] = (x[b,2j,c] + x[b,2j+1,c]) * k,  cD = (x_even - x_odd) * k
// d_out = [cA flat | cD flat].
//
// Pure streaming (268 MB, zero reuse): 4 pair-rows per block, float4 lanes,
// nontemporal loads/stores (native clang vector type — HIP float4 is a class
// the builtin rejects).

#define NPAIR (8 * 2048)        // total pair-rows
#define ROWS_PER_BLOCK 4
#define NPAIR_VEC (NPAIR * 256) // vec4 elements per output half

typedef float f4 __attribute__((ext_vector_type(4)));

__global__ __launch_bounds__(256) void dwt_haar_kernel(
    const f4* __restrict__ x,
    f4* __restrict__ cA,
    f4* __restrict__ cD)
{
    const float k = 0.7071067811865476f;
    const int t = threadIdx.x;                   // vec4 column 0..255
    const int r0 = blockIdx.x * ROWS_PER_BLOCK;  // first pair-row of block

#pragma unroll
    for (int j = 0; j < ROWS_PER_BLOCK; ++j) {
        const int r = r0 + j;
        const int e = r * 512 + t;               // even input row, vec4 units

        const f4 a = __builtin_nontemporal_load(&x[e]);
        const f4 b = __builtin_nontemporal_load(&x[e + 256]);

        const f4 s = (a + b) * k;
        const f4 d = (a - b) * k;

        const int o = r * 256 + t;
        __builtin_nontemporal_store(s, &cA[o]);
        __builtin_nontemporal_store(d, &cD[o]);
    }
}

extern "C" void kernel_launch(void* const* d_in, const int* in_sizes, int n_in,
                              void* d_out, int out_size, void* d_ws, size_t ws_size,
                              hipStream_t stream)
{
    const f4* x = (const f4*)d_in[0];
    f4* cA = (f4*)d_out;
    f4* cD = cA + NPAIR_VEC;

    const int nblocks = NPAIR / ROWS_PER_BLOCK;  // 4096
    dwt_haar_kernel<<<nblocks, 256, 0, stream>>>(x, cA, cD);
}